// Round 4
// baseline (40206.531 us; speedup 1.0000x reference)
//
#include <hip/hip_runtime.h>
#include <hip/hip_bf16.h>
#include <math.h>

// ---------------------------------------------------------------------------
// Round 4: ONE persistent kernel for the whole 512-step 2-layer LSTM + FC.
//  - 132 blocks: 0..63 layer0 (16 gate-cols each), 64..127 layer1, 128..131 FC.
//  - No LDS / no __syncthreads in GEMM: direct global->MFMA-fragment loads.
//  - Cross-block dataflow via per-step flags (agent-scope atomics + fences).
//  - c-state in registers for all 512 steps; h in 4-slot ring buffers (bf16).
// ws: bf16 weights 26.4MB + h rings 1MB + flags 0.2MB = 27.6MB
// ---------------------------------------------------------------------------

#define S_LEN 512
#define B_SZ  64
#define V_SZ  128
#define H_SZ  1024
#define G4    4096
#define BH    65536
#define FPAD  32          // ints per flag slot (128B line)

typedef unsigned short u16x8 __attribute__((ext_vector_type(8)));
typedef __bf16         bf16x8 __attribute__((ext_vector_type(8)));
typedef float          f32x4  __attribute__((ext_vector_type(4)));

__device__ __forceinline__ unsigned short f2bf(float f) {
    unsigned int u = __float_as_uint(f);
    u += 0x7fffu + ((u >> 16) & 1u);
    return (unsigned short)(u >> 16);
}

__device__ __forceinline__ f32x4 mfma16(u16x8 a, u16x8 b, f32x4 c) {
    return __builtin_amdgcn_mfma_f32_16x16x32_bf16(
        __builtin_bit_cast(bf16x8, a), __builtin_bit_cast(bf16x8, b), c, 0, 0, 0);
}

__global__ __launch_bounds__(256) void cvt_kernel(const float* __restrict__ s,
                                                  unsigned short* __restrict__ d, int n)
{
    int i = (blockIdx.x * 256 + threadIdx.x) * 4;
    if (i >= n) return;
    float4 v = *(const float4*)(s + i);
    ushort4 o;
    o.x = f2bf(v.x); o.y = f2bf(v.y); o.z = f2bf(v.z); o.w = f2bf(v.w);
    *(ushort4*)(d + i) = o;
}

// ---- dataflow sync ----
__device__ __forceinline__ void block_wait(int* f, int target) {
    if (threadIdx.x == 0) {
        while (__hip_atomic_load(f, __ATOMIC_ACQUIRE, __HIP_MEMORY_SCOPE_AGENT) < target)
            __builtin_amdgcn_s_sleep(8);
    }
    __syncthreads();
    __threadfence();   // device-scope acquire: invalidate stale L1/L2 lines
}
__device__ __forceinline__ void block_signal(int* f) {
    __syncthreads();   // all threads' stores drained (vmcnt(0) before barrier)
    if (threadIdx.x == 0) {
        __threadfence();   // writeback to coherent point
        __hip_atomic_fetch_add(f, 1, __ATOMIC_RELEASE, __HIP_MEMORY_SCOPE_AGENT);
    }
}

__global__ __launch_bounds__(256) void persist_kernel(
    const float* __restrict__ x,
    const unsigned short* __restrict__ Wih0, const unsigned short* __restrict__ Whh0,
    const unsigned short* __restrict__ Wih1, const unsigned short* __restrict__ Whh1,
    const unsigned short* __restrict__ Wfc,
    const float* __restrict__ bih0, const float* __restrict__ bhh0,
    const float* __restrict__ bih1, const float* __restrict__ bhh1,
    const float* __restrict__ bfc,
    unsigned short* __restrict__ h0b, unsigned short* __restrict__ h1b,
    int* __restrict__ flag0, int* __restrict__ flag1, int* __restrict__ flagF,
    float* __restrict__ out)
{
    __shared__ float sLg[16][132];
    const int bid  = blockIdx.x;
    const int tid  = threadIdx.x;
    const int wave = tid >> 6, lane = tid & 63;
    const int col  = lane & 15, kg8 = (lane >> 4) * 8;

    if (bid < 128) {
        // ========================= layer blocks =========================
        const bool L1 = (bid >= 64);
        const int  j0 = (bid & 63) * 16;
        const int  jj = j0 + col;
        const unsigned short* W1 = L1 ? Wih1 : Wih0;
        const unsigned short* W2 = L1 ? Whh1 : Whh0;
        const int  K1 = L1 ? H_SZ : V_SZ;
        const float* bi = L1 ? bih1 : bih0;
        const float* bh = L1 ? bhh1 : bhh0;
        const float bii = bi[jj]            + bh[jj];
        const float bif = bi[H_SZ + jj]     + bh[H_SZ + jj];
        const float big = bi[2 * H_SZ + jj] + bh[2 * H_SZ + jj];
        const float bio = bi[3 * H_SZ + jj] + bh[3 * H_SZ + jj];

        const unsigned short* w1p[4];
        const unsigned short* w2p[4];
        #pragma unroll
        for (int g = 0; g < 4; ++g) {
            w1p[g] = W1 + (long)(g * H_SZ + jj) * K1   + kg8;
            w2p[g] = W2 + (long)(g * H_SZ + jj) * H_SZ + kg8;
        }
        const int arow = wave * 16 + col;     // batch row of this lane's A-frag
        unsigned short* hring = L1 ? h1b : h0b;
        const unsigned short* hprev_ring = L1 ? h1b : h0b;   // recurrent input ring
        float creg[4] = {0.f, 0.f, 0.f, 0.f};

        for (int t = 0; t < S_LEN; ++t) {
            // dependency + WAR waits
            if (!L1) {
                if (t >= 1) block_wait(flag0 + (t - 1) * FPAD, 64);   // h0[t-1]
                if (t >= 4) block_wait(flag1 + (t - 4) * FPAD, 64);   // slot reuse
            } else {
                block_wait(flag0 + t * FPAD, 64);                     // h0[t]
                if (t >= 1) block_wait(flag1 + (t - 1) * FPAD, 64);   // h1[t-1]
                if (t >= 4) block_wait(flagF + (t - 4) * FPAD, 4);    // slot reuse
            }

            f32x4 acc[4][2] = {};

            // ---- pass 1: input projection ----
            if (!L1) {
                const float* xp = x + (long)arow * (S_LEN * V_SZ) + (long)t * V_SZ + kg8;
                #pragma unroll
                for (int i = 0; i < 4; ++i) {               // K=128
                    float4 u = *(const float4*)(xp + i * 32);
                    float4 v = *(const float4*)(xp + i * 32 + 4);
                    u16x8 af;
                    af[0] = f2bf(u.x); af[1] = f2bf(u.y); af[2] = f2bf(u.z); af[3] = f2bf(u.w);
                    af[4] = f2bf(v.x); af[5] = f2bf(v.y); af[6] = f2bf(v.z); af[7] = f2bf(v.w);
                    #pragma unroll
                    for (int g = 0; g < 4; ++g)
                        acc[g][i & 1] = mfma16(af, *(const u16x8*)(w1p[g] + i * 32), acc[g][i & 1]);
                }
            } else {
                const unsigned short* ap = h0b + (size_t)(t & 3) * BH + (long)arow * H_SZ + kg8;
                #pragma unroll 4
                for (int i = 0; i < 32; ++i) {              // K=1024
                    u16x8 af = *(const u16x8*)(ap + i * 32);
                    #pragma unroll
                    for (int g = 0; g < 4; ++g)
                        acc[g][i & 1] = mfma16(af, *(const u16x8*)(w1p[g] + i * 32), acc[g][i & 1]);
                }
            }

            // ---- pass 2: recurrent projection (skip at t=0: h=0) ----
            if (t >= 1) {
                const unsigned short* ap = hprev_ring + (size_t)((t - 1) & 3) * BH
                                         + (long)arow * H_SZ + kg8;
                #pragma unroll 4
                for (int i = 0; i < 32; ++i) {
                    u16x8 af = *(const u16x8*)(ap + i * 32);
                    #pragma unroll
                    for (int g = 0; g < 4; ++g)
                        acc[g][i & 1] = mfma16(af, *(const u16x8*)(w2p[g] + i * 32), acc[g][i & 1]);
                }
            }

            // ---- fused LSTM update (lane-local, c in registers) ----
            unsigned short* hout = hring + (size_t)(t & 3) * BH;
            #pragma unroll
            for (int r = 0; r < 4; ++r) {
                const int m = wave * 16 + (lane >> 4) * 4 + r;
                const float ip = acc[0][0][r] + acc[0][1][r] + bii;
                const float fp = acc[1][0][r] + acc[1][1][r] + bif;
                const float gp = acc[2][0][r] + acc[2][1][r] + big;
                const float op = acc[3][0][r] + acc[3][1][r] + bio;
                const float iv = 1.f / (1.f + expf(-ip));
                const float fv = 1.f / (1.f + expf(-fp));
                const float gv = tanhf(gp);
                const float ov = 1.f / (1.f + expf(-op));
                const float cv = fv * creg[r] + iv * gv;
                creg[r] = cv;
                hout[(long)m * H_SZ + jj] = f2bf(ov * tanhf(cv));
            }

            block_signal((L1 ? flag1 : flag0) + t * FPAD);
        }
        return;
    }

    // ============================ FC blocks ============================
    {
        const int m0 = (bid - 128) * 16;
        const unsigned short* wp[2];
        #pragma unroll
        for (int nt = 0; nt < 2; ++nt)
            wp[nt] = Wfc + (long)(wave * 32 + nt * 16 + col) * H_SZ + kg8;

        for (int t = 0; t < S_LEN; ++t) {
            block_wait(flag1 + t * FPAD, 64);

            const unsigned short* ap = h1b + (size_t)(t & 3) * BH
                                     + (long)(m0 + col) * H_SZ + kg8;
            f32x4 acc[2][2] = {};
            #pragma unroll 4
            for (int i = 0; i < 32; ++i) {
                u16x8 af = *(const u16x8*)(ap + i * 32);
                #pragma unroll
                for (int nt = 0; nt < 2; ++nt)
                    acc[nt][i & 1] = mfma16(af, *(const u16x8*)(wp[nt] + i * 32), acc[nt][i & 1]);
            }
            #pragma unroll
            for (int nt = 0; nt < 2; ++nt)
                #pragma unroll
                for (int r = 0; r < 4; ++r) {
                    const int m = (lane >> 4) * 4 + r;
                    const int n = wave * 32 + nt * 16 + col;
                    sLg[m][n] = acc[nt][0][r] + acc[nt][1][r] + bfc[n];
                }
            __syncthreads();
            const int row = tid >> 4, sub = tid & 15;
            float vals[8]; float mx = -1e30f;
            #pragma unroll
            for (int q = 0; q < 8; ++q) { vals[q] = sLg[row][sub * 8 + q]; mx = fmaxf(mx, vals[q]); }
            #pragma unroll
            for (int o = 1; o < 16; o <<= 1) mx = fmaxf(mx, __shfl_xor(mx, o));
            float se = 0.f;
            #pragma unroll
            for (int q = 0; q < 8; ++q) se += expf(vals[q] - mx);
            #pragma unroll
            for (int o = 1; o < 16; o <<= 1) se += __shfl_xor(se, o);
            const float ls = mx + logf(se);
            float* op = out + (long)(m0 + row) * S_LEN * V_SZ + (long)t * V_SZ + sub * 8;
            #pragma unroll
            for (int q = 0; q < 8; ++q) op[q] = vals[q] - ls;

            block_signal(flagF + t * FPAD);
        }
    }
}

// =============================== launcher ==================================
extern "C" void kernel_launch(void* const* d_in, const int* in_sizes, int n_in,
                              void* d_out, int out_size, void* d_ws, size_t ws_size,
                              hipStream_t stream)
{
    const float* x    = (const float*)d_in[0];
    const float* Wih0 = (const float*)d_in[1];
    const float* Whh0 = (const float*)d_in[2];
    const float* bih0 = (const float*)d_in[3];
    const float* bhh0 = (const float*)d_in[4];
    const float* Wih1 = (const float*)d_in[5];
    const float* Whh1 = (const float*)d_in[6];
    const float* bih1 = (const float*)d_in[7];
    const float* bhh1 = (const float*)d_in[8];
    const float* Wfc  = (const float*)d_in[9];
    const float* bfc  = (const float*)d_in[10];
    float* out = (float*)d_out;

    unsigned short* wih0 = (unsigned short*)d_ws;              // 4096*128
    unsigned short* whh0 = wih0 + (size_t)G4 * V_SZ;           // 4096*1024
    unsigned short* wih1 = whh0 + (size_t)G4 * H_SZ;
    unsigned short* whh1 = wih1 + (size_t)G4 * H_SZ;
    unsigned short* wfc  = whh1 + (size_t)G4 * H_SZ;           // 128*1024
    unsigned short* h0b  = wfc  + (size_t)V_SZ * H_SZ;         // 4 slots bf16
    unsigned short* h1b  = h0b + 4 * (size_t)BH;
    int* flags = (int*)(h1b + 4 * (size_t)BH);                 // 3*512*FPAD ints
    int* flag0 = flags;
    int* flag1 = flag0 + S_LEN * FPAD;
    int* flagF = flag1 + S_LEN * FPAD;

    auto cvt = [&](const float* s, unsigned short* d, int n) {
        cvt_kernel<<<(n / 4 + 255) / 256, 256, 0, stream>>>(s, d, n);
    };
    cvt(Wih0, wih0, G4 * V_SZ);
    cvt(Whh0, whh0, G4 * H_SZ);
    cvt(Wih1, wih1, G4 * H_SZ);
    cvt(Whh1, whh1, G4 * H_SZ);
    cvt(Wfc,  wfc,  V_SZ * H_SZ);
    hipMemsetAsync(flags, 0, (size_t)3 * S_LEN * FPAD * sizeof(int), stream);

    persist_kernel<<<132, 256, 0, stream>>>(
        x, wih0, whh0, wih1, whh1, wfc,
        bih0, bhh0, bih1, bhh1, bfc,
        h0b, h1b, flag0, flag1, flagF, out);
}

// Round 5
// 6228.624 us; speedup vs baseline: 6.4551x; 6.4551x over previous
//
#include <hip/hip_runtime.h>
#include <hip/hip_bf16.h>
#include <math.h>

// ---------------------------------------------------------------------------
// Round 5: persistent kernel, LDS-resident weights, fence-free sc0/sc1 dataflow.
//  196 blocks x 256 thr: [0,64) layer0 (16 cols), [64,192) layer1 (8 cols),
//  [192,196) FC+logsoftmax (16 batch rows).
//  - Weights staged to LDS once (<=149.5KB/block), read all 512 steps.
//  - h state: 8-slot rings, stores/loads via sc0 sc1 (coherence point), no fences.
//  - flags: per-producer step counters, sc0/sc1 store + spin-load. No atomics.
//  - A-fragment loads: counted s_waitcnt vmcnt(8) pipeline + sched_barrier(0).
// ---------------------------------------------------------------------------

#define S_LEN 512
#define B_SZ  64
#define V_SZ  128
#define H_SZ  1024
#define BH    65536
#define RING  8
#define FSTR  16      // ints per flag slot (64B)

typedef unsigned short u16;
typedef unsigned short u16x8 __attribute__((ext_vector_type(8)));
typedef __bf16         bf16x8 __attribute__((ext_vector_type(8)));
typedef float          f32x4  __attribute__((ext_vector_type(4)));
typedef int            i32x4  __attribute__((ext_vector_type(4)));

__device__ __forceinline__ u16 f2bf(float f) {
    unsigned int u = __float_as_uint(f);
    u += 0x7fffu + ((u >> 16) & 1u);
    return (u16)(u >> 16);
}
__device__ __forceinline__ f32x4 mfma16(u16x8 a, u16x8 b, f32x4 c) {
    return __builtin_amdgcn_mfma_f32_16x16x32_bf16(
        __builtin_bit_cast(bf16x8, a), __builtin_bit_cast(bf16x8, b), c, 0, 0, 0);
}
__device__ __forceinline__ f32x4 mfma16(i32x4 a, u16x8 b, f32x4 c) {
    return __builtin_amdgcn_mfma_f32_16x16x32_bf16(
        __builtin_bit_cast(bf16x8, a), __builtin_bit_cast(bf16x8, b), c, 0, 0, 0);
}

// ---- coherent (cross-XCD) memory ops: bypass L1/L2, no cache invalidation ----
__device__ __forceinline__ void ld_coh(i32x4& d, const u16* p) {
    asm volatile("global_load_dwordx4 %0, %1, off sc0 sc1" : "=v"(d) : "v"(p));
}
__device__ __forceinline__ void st_coh_u16(u16* p, u16 v) {
    unsigned int vv = v;
    asm volatile("global_store_short %0, %1, off sc0 sc1" :: "v"(p), "v"(vv));
}
__device__ __forceinline__ int ld_flag(const int* p) {
    int v;
    asm volatile("global_load_dword %0, %1, off sc0 sc1\n\ts_waitcnt vmcnt(0)"
                 : "=v"(v) : "v"(p) : "memory");
    return v;
}
__device__ __forceinline__ void st_flag(int* p, int v) {
    asm volatile("global_store_dword %0, %1, off sc0 sc1" :: "v"(p), "v"(v));
}
#define WAITV(n) asm volatile("s_waitcnt vmcnt(" #n ")" ::: "memory")
#define SCHEDB   __builtin_amdgcn_sched_barrier(0)

__global__ __launch_bounds__(256) void cvt_kernel(const float* __restrict__ s,
                                                  u16* __restrict__ d, int n)
{
    int i = (blockIdx.x * 256 + threadIdx.x) * 4;
    if (i >= n) return;
    float4 v = *(const float4*)(s + i);
    ushort4 o;
    o.x = f2bf(v.x); o.y = f2bf(v.y); o.z = f2bf(v.z); o.w = f2bf(v.w);
    *(ushort4*)(d + i) = o;
}

union SMemL {
    struct { u16 wih[64 * 136]; u16 whh[64 * 1032]; } l0;   // 17408B + 132096B
    struct { u16 w[64 * 1032]; } l1;                        // 132096B
    float lg[16][132];                                      // 8448B
};

__global__ __launch_bounds__(256, 1) void persist_kernel(
    const float* __restrict__ x,
    const u16* __restrict__ Wih0c, const u16* __restrict__ Whh0c,
    const u16* __restrict__ Wih1c, const u16* __restrict__ Whh1c,
    const u16* __restrict__ Wfcc,
    const float* __restrict__ bih0, const float* __restrict__ bhh0,
    const float* __restrict__ bih1, const float* __restrict__ bhh1,
    const float* __restrict__ bfc,
    u16* __restrict__ h0b, u16* __restrict__ h1b,
    int* __restrict__ flagL0, int* __restrict__ flagL1, int* __restrict__ flagFC,
    float* __restrict__ out)
{
    __shared__ SMemL sm;
    const int bid = blockIdx.x, tid = threadIdx.x;
    const int wave = tid >> 6, lane = tid & 63;
    const int l16 = lane & 15, kgi = lane >> 4, kg8 = kgi * 8;

    // ======================= LAYER 0 : blocks 0..63 =======================
    if (bid < 64) {
        const int j0 = bid * 16, jj = j0 + l16;
        for (int ch = tid; ch < 1024; ch += 256) {          // Wih0 slice
            int rr = ch >> 4, kc = (ch & 15) * 8;
            int gr = (rr >> 4) * H_SZ + j0 + (rr & 15);
            *(u16x8*)&sm.l0.wih[rr * 136 + kc] = *(const u16x8*)(Wih0c + (size_t)gr * V_SZ + kc);
        }
        for (int ch = tid; ch < 8192; ch += 256) {          // Whh0 slice
            int rr = ch >> 7, kc = (ch & 127) * 8;
            int gr = (rr >> 4) * H_SZ + j0 + (rr & 15);
            *(u16x8*)&sm.l0.whh[rr * 1032 + kc] = *(const u16x8*)(Whh0c + (size_t)gr * H_SZ + kc);
        }
        __syncthreads();

        const float bii = bih0[jj]            + bhh0[jj];
        const float bif = bih0[H_SZ + jj]     + bhh0[H_SZ + jj];
        const float big = bih0[2 * H_SZ + jj] + bhh0[2 * H_SZ + jj];
        const float bio = bih0[3 * H_SZ + jj] + bhh0[3 * H_SZ + jj];

        const u16* wihB[4]; const u16* whhB[4];
        #pragma unroll
        for (int g = 0; g < 4; ++g) {
            wihB[g] = &sm.l0.wih[(g * 16 + l16) * 136 + kg8];
            whhB[g] = &sm.l0.whh[(g * 16 + l16) * 1032 + kg8];
        }
        const int arow = wave * 16 + l16;
        const float* xrow = x + (size_t)arow * (S_LEN * V_SZ);
        float creg[4] = {0.f, 0.f, 0.f, 0.f};

        for (int t = 0; t < S_LEN; ++t) {
            // combined wait: h0[t-1] (all 64 L0) + WAR h0 slot (L1 done t-8)
            {
                const int* p = nullptr; int tgt = 0;
                if (tid < 64)               { p = flagL0 + tid * FSTR;        tgt = t; }
                else if (tid < 192 && t >= 8) { p = flagL1 + (tid - 64) * FSTR; tgt = t - 7; }
                if (p && tgt > 0) while (ld_flag(p) < tgt) __builtin_amdgcn_s_sleep(2);
                __syncthreads();
            }

            f32x4 acc[4][2] = {};
            // pass 1: x_t (normal cached loads, fp32 -> bf16)
            {
                const float* xp = xrow + (size_t)t * V_SZ + kg8;
                #pragma unroll
                for (int i = 0; i < 4; ++i) {
                    float4 u = *(const float4*)(xp + i * 32);
                    float4 v = *(const float4*)(xp + i * 32 + 4);
                    u16x8 af;
                    af[0] = f2bf(u.x); af[1] = f2bf(u.y); af[2] = f2bf(u.z); af[3] = f2bf(u.w);
                    af[4] = f2bf(v.x); af[5] = f2bf(v.y); af[6] = f2bf(v.z); af[7] = f2bf(v.w);
                    #pragma unroll
                    for (int g = 0; g < 4; ++g)
                        acc[g][i & 1] = mfma16(af, *(const u16x8*)(wihB[g] + i * 32), acc[g][i & 1]);
                }
            }

            // pass 2: h0[t-1] (sc-coherent, counted pipeline); slot 7 zeroed for t=0
            {
                auto ISSUE = [&](i32x4 (&buf)[8], const u16* base) {
                    #pragma unroll
                    for (int q = 0; q < 8; ++q) ld_coh(buf[q], base + q * 32);
                };
                auto COMP = [&](i32x4 (&buf)[8], int k0) {
                    #pragma unroll
                    for (int q = 0; q < 8; ++q) {
                        #pragma unroll
                        for (int g = 0; g < 4; ++g)
                            acc[g][q & 1] = mfma16(buf[q],
                                *(const u16x8*)(whhB[g] + (k0 + q) * 32), acc[g][q & 1]);
                    }
                };
                const u16* aB = h0b + (size_t)((t - 1) & 7) * BH + (size_t)arow * H_SZ + kg8;
                i32x4 b0[8], b1[8];
                WAITV(0);
                ISSUE(b0, aB);
                ISSUE(b1, aB + 256); WAITV(8); SCHEDB; COMP(b0, 0);
                ISSUE(b0, aB + 512); WAITV(8); SCHEDB; COMP(b1, 8);
                ISSUE(b1, aB + 768); WAITV(8); SCHEDB; COMP(b0, 16);
                                     WAITV(0); SCHEDB; COMP(b1, 24);
            }

            // fused LSTM update, h store (coherent)
            {
                u16* hout = h0b + (size_t)(t & 7) * BH;
                #pragma unroll
                for (int r = 0; r < 4; ++r) {
                    const int m = wave * 16 + kgi * 4 + r;
                    const float ip = acc[0][0][r] + acc[0][1][r] + bii;
                    const float fp = acc[1][0][r] + acc[1][1][r] + bif;
                    const float gp = acc[2][0][r] + acc[2][1][r] + big;
                    const float op = acc[3][0][r] + acc[3][1][r] + bio;
                    const float iv = 1.f / (1.f + expf(-ip));
                    const float fv = 1.f / (1.f + expf(-fp));
                    const float gv = tanhf(gp);
                    const float ov = 1.f / (1.f + expf(-op));
                    const float cv = fv * creg[r] + iv * gv;
                    creg[r] = cv;
                    st_coh_u16(hout + (size_t)m * H_SZ + jj, f2bf(ov * tanhf(cv)));
                }
                WAITV(0);
            }
            __syncthreads();
            if (tid == 0) st_flag(flagL0 + bid * FSTR, t + 1);
        }
        return;
    }

    // ======================= LAYER 1 : blocks 64..191 =======================
    if (bid < 192) {
        const int lb = bid - 64, j0 = lb * 8, jj2 = j0 + (l16 & 7);
        for (int ch = tid; ch < 8192; ch += 256) {
            int region = ch >> 12;                 // 0: Wih1, 1: Whh1
            int rl = (ch >> 7) & 31, kc = (ch & 127) * 8;
            int gr = (rl >> 3) * H_SZ + j0 + (rl & 7);
            const u16* src = (region ? Whh1c : Wih1c) + (size_t)gr * H_SZ + kc;
            *(u16x8*)&sm.l1.w[(region * 32 + rl) * 1032 + kc] = *(const u16x8*)src;
        }
        __syncthreads();

        const float bii = bih1[jj2]            + bhh1[jj2];
        const float bif = bih1[H_SZ + jj2]     + bhh1[H_SZ + jj2];
        const float big = bih1[2 * H_SZ + jj2] + bhh1[2 * H_SZ + jj2];
        const float bio = bih1[3 * H_SZ + jj2] + bhh1[3 * H_SZ + jj2];
        const bool lo = (l16 < 8);

        const u16* wB1[2]; const u16* wB2[2];
        #pragma unroll
        for (int nt = 0; nt < 2; ++nt) {
            wB1[nt] = &sm.l1.w[(nt * 16 + l16) * 1032 + kg8];
            wB2[nt] = &sm.l1.w[(32 + nt * 16 + l16) * 1032 + kg8];
        }
        const int arow = wave * 16 + l16;
        float creg[4] = {0.f, 0.f, 0.f, 0.f};

        for (int t = 0; t < S_LEN; ++t) {
            {
                const int* p = nullptr; int tgt = 0;
                if (tid < 64)                     { p = flagL0 + tid * FSTR;         tgt = t + 1; }
                else if (tid < 192)               { p = flagL1 + (tid - 64) * FSTR;  tgt = t; }
                else if (tid < 196 && t >= 8)     { p = flagFC + (tid - 192) * FSTR; tgt = t - 7; }
                if (p && tgt > 0) while (ld_flag(p) < tgt) __builtin_amdgcn_s_sleep(2);
                __syncthreads();
            }

            f32x4 acc[2][2] = {};
            {
                auto ISSUE = [&](i32x4 (&buf)[8], const u16* base) {
                    #pragma unroll
                    for (int q = 0; q < 8; ++q) ld_coh(buf[q], base + q * 32);
                };
                auto COMP = [&](i32x4 (&buf)[8], const u16* const (&wb)[2], int k0) {
                    #pragma unroll
                    for (int q = 0; q < 8; ++q) {
                        #pragma unroll
                        for (int nt = 0; nt < 2; ++nt)
                            acc[nt][q & 1] = mfma16(buf[q],
                                *(const u16x8*)(wb[nt] + (k0 + q) * 32), acc[nt][q & 1]);
                    }
                };
                const u16* a1 = h0b + (size_t)(t & 7) * BH + (size_t)arow * H_SZ + kg8;        // h0[t]
                const u16* a2 = h1b + (size_t)((t - 1) & 7) * BH + (size_t)arow * H_SZ + kg8;  // h1[t-1]
                i32x4 b0[8], b1[8];
                WAITV(0);
                ISSUE(b0, a1);
                ISSUE(b1, a1 + 256); WAITV(8); SCHEDB; COMP(b0, wB1, 0);
                ISSUE(b0, a1 + 512); WAITV(8); SCHEDB; COMP(b1, wB1, 8);
                ISSUE(b1, a1 + 768); WAITV(8); SCHEDB; COMP(b0, wB1, 16);
                ISSUE(b0, a2);       WAITV(8); SCHEDB; COMP(b1, wB1, 24);
                ISSUE(b1, a2 + 256); WAITV(8); SCHEDB; COMP(b0, wB2, 0);
                ISSUE(b0, a2 + 512); WAITV(8); SCHEDB; COMP(b1, wB2, 8);
                ISSUE(b1, a2 + 768); WAITV(8); SCHEDB; COMP(b0, wB2, 16);
                                     WAITV(0); SCHEDB; COMP(b1, wB2, 24);
            }

            // epilogue: tile0 = (i | f), tile1 = (g | o); pair-exchange via shfl_xor(8)
            {
                u16* hout = h1b + (size_t)(t & 7) * BH;
                #pragma unroll
                for (int r = 0; r < 4; ++r) {
                    const float s0 = acc[0][0][r] + acc[0][1][r];
                    const float s1 = acc[1][0][r] + acc[1][1][r];
                    const float q0 = __shfl_xor(s0, 8);
                    const float q1 = __shfl_xor(s1, 8);
                    const float ip = (lo ? s0 : q0) + bii;
                    const float fp = (lo ? q0 : s0) + bif;
                    const float gp = (lo ? s1 : q1) + big;
                    const float op = (lo ? q1 : s1) + bio;
                    const float iv = 1.f / (1.f + expf(-ip));
                    const float fv = 1.f / (1.f + expf(-fp));
                    const float gv = tanhf(gp);
                    const float ov = 1.f / (1.f + expf(-op));
                    const float cv = fv * creg[r] + iv * gv;
                    creg[r] = cv;
                    if (lo) {
                        const int m = wave * 16 + kgi * 4 + r;
                        st_coh_u16(hout + (size_t)m * H_SZ + jj2, f2bf(ov * tanhf(cv)));
                    }
                }
                WAITV(0);
            }
            __syncthreads();
            if (tid == 0) st_flag(flagL1 + lb * FSTR, t + 1);
        }
        return;
    }

    // ======================= FC : blocks 192..195 =======================
    {
        const int fb = bid - 192, m0 = fb * 16;
        const u16* wp[2];
        #pragma unroll
        for (int nt = 0; nt < 2; ++nt)
            wp[nt] = Wfcc + (size_t)(wave * 32 + nt * 16 + l16) * H_SZ + kg8;

        for (int t = 0; t < S_LEN; ++t) {
            {
                const int* p = nullptr; int tgt = 0;
                if (tid < 128) { p = flagL1 + tid * FSTR; tgt = t + 1; }
                if (p && tgt > 0) while (ld_flag(p) < tgt) __builtin_amdgcn_s_sleep(2);
                __syncthreads();
            }

            const u16* aB = h1b + (size_t)(t & 7) * BH + (size_t)(m0 + l16) * H_SZ + kg8;
            f32x4 acc[2][2] = {};
            i32x4 buf[8];
            WAITV(0);
            #pragma unroll
            for (int c = 0; c < 4; ++c) {
                #pragma unroll
                for (int q = 0; q < 8; ++q) ld_coh(buf[q], aB + c * 256 + q * 32);
                WAITV(0); SCHEDB;
                #pragma unroll
                for (int q = 0; q < 8; ++q) {
                    #pragma unroll
                    for (int nt = 0; nt < 2; ++nt)
                        acc[nt][q & 1] = mfma16(buf[q],
                            *(const u16x8*)(wp[nt] + (c * 8 + q) * 32), acc[nt][q & 1]);
                }
            }
            #pragma unroll
            for (int nt = 0; nt < 2; ++nt)
                #pragma unroll
                for (int r = 0; r < 4; ++r) {
                    const int m = kgi * 4 + r, n = wave * 32 + nt * 16 + l16;
                    sm.lg[m][n] = acc[nt][0][r] + acc[nt][1][r] + bfc[n];
                }
            __syncthreads();
            const int row = tid >> 4, sub = tid & 15;
            float vals[8]; float mx = -1e30f;
            #pragma unroll
            for (int q = 0; q < 8; ++q) { vals[q] = sm.lg[row][sub * 8 + q]; mx = fmaxf(mx, vals[q]); }
            #pragma unroll
            for (int o = 1; o < 16; o <<= 1) mx = fmaxf(mx, __shfl_xor(mx, o));
            float se = 0.f;
            #pragma unroll
            for (int q = 0; q < 8; ++q) se += expf(vals[q] - mx);
            #pragma unroll
            for (int o = 1; o < 16; o <<= 1) se += __shfl_xor(se, o);
            const float ls = mx + logf(se);
            float* op = out + (size_t)(m0 + row) * (S_LEN * V_SZ) + (size_t)t * V_SZ + sub * 8;
            #pragma unroll
            for (int q = 0; q < 8; ++q) op[q] = vals[q] - ls;

            __syncthreads();
            if (tid == 0) st_flag(flagFC + fb * FSTR, t + 1);
        }
    }
}

// =============================== launcher ==================================
extern "C" void kernel_launch(void* const* d_in, const int* in_sizes, int n_in,
                              void* d_out, int out_size, void* d_ws, size_t ws_size,
                              hipStream_t stream)
{
    const float* x    = (const float*)d_in[0];
    const float* Wih0 = (const float*)d_in[1];
    const float* Whh0 = (const float*)d_in[2];
    const float* bih0 = (const float*)d_in[3];
    const float* bhh0 = (const float*)d_in[4];
    const float* Wih1 = (const float*)d_in[5];
    const float* Whh1 = (const float*)d_in[6];
    const float* bih1 = (const float*)d_in[7];
    const float* bhh1 = (const float*)d_in[8];
    const float* Wfc  = (const float*)d_in[9];
    const float* bfc  = (const float*)d_in[10];
    float* out = (float*)d_out;

    u16* wih0 = (u16*)d_ws;                                  // 4096*128
    u16* whh0 = wih0 + (size_t)4096 * 128;                   // 4096*1024
    u16* wih1 = whh0 + (size_t)4096 * 1024;
    u16* whh1 = wih1 + (size_t)4096 * 1024;
    u16* wfc  = whh1 + (size_t)4096 * 1024;                  // 128*1024
    u16* h0b  = wfc  + (size_t)128 * 1024;                   // RING slots
    u16* h1b  = h0b + (size_t)RING * BH;
    int* flags  = (int*)(h1b + (size_t)RING * BH);           // 196*FSTR ints
    int* flagL0 = flags;
    int* flagL1 = flagL0 + 64 * FSTR;
    int* flagFC = flagL1 + 128 * FSTR;

    auto cvt = [&](const float* s, u16* d, int n) {
        cvt_kernel<<<(n / 4 + 255) / 256, 256, 0, stream>>>(s, d, n);
    };
    cvt(Wih0, wih0, 4096 * 128);
    cvt(Whh0, whh0, 4096 * 1024);
    cvt(Wih1, wih1, 4096 * 1024);
    cvt(Whh1, whh1, 4096 * 1024);
    cvt(Wfc,  wfc,  128 * 1024);
    hipMemsetAsync(h0b, 0, (size_t)2 * RING * BH * sizeof(u16), stream);
    hipMemsetAsync(flags, 0, (size_t)196 * FSTR * sizeof(int), stream);

    persist_kernel<<<196, 256, 0, stream>>>(
        x, wih0, whh0, wih1, whh1, wfc,
        bih0, bhh0, bih1, bhh1, bfc,
        h0b, h1b, flagL0, flagL1, flagFC, out);
}